// Round 5
// baseline (163.752 us; speedup 1.0000x reference)
//
#include <hip/hip_runtime.h>
#include <math.h>

// Problem: B=8, T=8192, D=128, E=8, I=16.  BT = 65536 tokens.
// Outputs concatenated f32: out0 [BT,128] | out1 [BT,8] | out2 [BT,8,128]
// R5: persistent 2-tile blocks: 512 blocks x 128 tokens, one co-resident
// generation; tile-2 prologue hidden under tile-1 store phase.
#define O1_OFF 8388608
#define O2_OFF 8912896

typedef __attribute__((ext_vector_type(8))) short short8;
typedef __attribute__((ext_vector_type(4))) float f32x4;

static __device__ __forceinline__ unsigned short f2bf(float f) {
    unsigned u = __builtin_bit_cast(unsigned, f);
    u = (u + 0x7fffu + ((u >> 16) & 1u)) >> 16;   // RNE
    return (unsigned short)u;
}

// swizzled byte offset inside a [rows][16 x 16B-chunks] LDS region (weights/xn/y)
static __device__ __forceinline__ int swz(int row, int chunk) {
    return row * 256 + ((chunk ^ (row & 7)) << 4);
}

// transpose-region byte offset: [row 0..63][col 0..127] bf16, 256B/row.
static __device__ __forceinline__ int tswz(int row, int col) {
    int chunk = (col >> 3) ^ ((row >> 1) & 6);
    return row * 256 + (chunk << 4) + ((col & 7) << 1);
}

// LDS-only barrier: does NOT drain vmcnt -> global stores stay in flight.
static __device__ __forceinline__ void bar_lds() {
    asm volatile("s_waitcnt lgkmcnt(0)" ::: "memory");
    __builtin_amdgcn_s_barrier();
    asm volatile("" ::: "memory");
}

// within-wave LDS fence: drain DS ops + block compiler (TBAA) reordering
static __device__ __forceinline__ void fence_lds() {
    asm volatile("s_waitcnt lgkmcnt(0)" ::: "memory");
}

__global__ __launch_bounds__(256, 2) void moe_fused(
    const float* __restrict__ x, const float* __restrict__ ln_g,
    const float* __restrict__ ln_b, const float* __restrict__ gate_w,
    const float* __restrict__ gate_b, const float* __restrict__ w1,
    const float* __restrict__ w2, float* __restrict__ out)
{
    // 66 KB: 2 blocks/CU
    __shared__ __align__(16) char smem[67584];
    char* pXY = smem;                      // 16KB: xn (bf16), then y (bf16)
    char* pW  = smem + 16384;              // 32KB: w1t -> w2t -> agg -> w1t -> ...
    char* pTR = smem + 49152;              // 16KB: bf16 transpose buffer (out2 tiles)
    float* pRW = (float*)(smem + 65536);   // 2KB: routing weights [64][8] f32

    const int t = threadIdx.x;
    const int l = t & 63;
    const int w = t >> 6;
    const int tok0a = blockIdx.x * 128;    // tile 1
    const int tok0b = tok0a + 64;          // tile 2

    const int colq = (t & 31) * 4;   // P0-layout columns
    const int rsub = t >> 5;         // P0-layout row sub-index

    const int rb = w * 16;           // wave's 16 token rows
    const int col = l & 15;          // MFMA n / lane col (token index in tiles)
    const int ak = l >> 4;           // MFMA k-subgroup / token 4-row group
    const int arow = rb + col;
    const int e2 = t >> 5;

    const f32x4 zero4 = {0.f, 0.f, 0.f, 0.f};
    const short8 zfrag = {0, 0, 0, 0, 0, 0, 0, 0};

    float4 xv1[8], xv2[8];           // x tiles in regs
    unsigned pk[4][8];               // w2 bf16-packed, persists both tiles
    short8 wbuf[8];                  // w1 staging slice (tile-2 reload)
    short8 gfr[4];                   // gate fragments, persist
    float4 g4, b4, gb4;

    //================ phase lambdas (R4-verified bodies) ================
    auto load_x = [&](float4 xv[8], int tok0) {
        const float* xb = x + (size_t)tok0 * 128;
        #pragma unroll
        for (int s = 0; s < 8; ++s)
            xv[s] = *(const float4*)(xb + s * 1024 + t * 4);
    };

    auto w1_loads = [&]() {          // global -> wbuf (bf16-packed)
        const int p = t & 127, ch = t >> 7;
        const float* w1b = w1 + (p >> 4) * 2048 + (p & 15);   // w1[e][c][i]
        #pragma unroll
        for (int cc = 0; cc < 8; ++cc) {
            short8 v;
            #pragma unroll
            for (int j = 0; j < 8; ++j)
                v[j] = (short)f2bf(w1b[(ch * 64 + cc * 8 + j) * 16]);
            wbuf[cc] = v;
        }
    };
    auto w1_writes = [&]() {         // wbuf -> w1t (pW), swizzled
        const int p = t & 127, ch = t >> 7;
        #pragma unroll
        for (int cc = 0; cc < 8; ++cc)
            *(short8*)(pW + swz(p, ch * 8 + cc)) = wbuf[cc];
    };

    auto ln_to_lds = [&](const float4 xv[8]) {
        #pragma unroll
        for (int s = 0; s < 8; ++s) {
            float4 v = xv[s];
            float sm = v.x + v.y + v.z + v.w;
            float sq = v.x*v.x + v.y*v.y + v.z*v.z + v.w*v.w;
            #pragma unroll
            for (int m = 1; m < 32; m <<= 1) {
                sm += __shfl_xor(sm, m, 64);
                sq += __shfl_xor(sq, m, 64);
            }
            float mu = sm * (1.0f / 128.0f);
            float var = sq * (1.0f / 128.0f) - mu * mu;
            float rs = rsqrtf(var + 1e-5f);
            float n0 = (v.x - mu) * rs * g4.x + b4.x;
            float n1 = (v.y - mu) * rs * g4.y + b4.y;
            float n2 = (v.z - mu) * rs * g4.z + b4.z;
            float n3 = (v.w - mu) * rs * g4.w + b4.w;
            unsigned lo = (unsigned)f2bf(n0) | ((unsigned)f2bf(n1) << 16);
            unsigned hi = (unsigned)f2bf(n2) | ((unsigned)f2bf(n3) << 16);
            unsigned long long dvv = (unsigned long long)lo | ((unsigned long long)hi << 32);
            int row = s * 8 + rsub;
            *(unsigned long long*)(pXY + swz(row, colq >> 3) + (colq & 7) * 2) = dvv;
        }
    };

    auto gating = [&](short8 afr[4], int tok0) {
        #pragma unroll
        for (int ks = 0; ks < 4; ++ks)
            afr[ks] = *(const short8*)(pXY + swz(arow, ks * 4 + ak));
        f32x4 accg = zero4;
        #pragma unroll
        for (int ks = 0; ks < 4; ++ks)
            accg = __builtin_amdgcn_mfma_f32_16x16x32_bf16(gfr[ks], afr[ks], accg, 0, 0, 0);
        const size_t trow = (size_t)(tok0 + arow);
        float lg0 = accg[0] + gb4.x;
        float lg1 = accg[1] + gb4.y;
        float lg2 = accg[2] + gb4.z;
        float lg3 = accg[3] + gb4.w;
        if (ak < 2) {
            f32x4 lgv = {lg0, lg1, lg2, lg3};
            *(f32x4*)(out + O1_OFF + trow * 8 + ak * 4) = lgv;
        }
        float mx = fmaxf(fmaxf(lg0, lg1), fmaxf(lg2, lg3));
        mx = fmaxf(mx, __shfl_xor(mx, 16, 64));
        float ex0 = __expf(lg0 - mx), ex1 = __expf(lg1 - mx);
        float ex2 = __expf(lg2 - mx), ex3 = __expf(lg3 - mx);
        float sm = ex0 + ex1 + ex2 + ex3;
        sm += __shfl_xor(sm, 16, 64);
        float inv = 1.0f / sm;
        if (ak < 2) {
            f32x4 pv = {ex0 * inv, ex1 * inv, ex2 * inv, ex3 * inv};
            *(f32x4*)(pRW + arow * 8 + ak * 4) = pv;
        }
    };

    auto stageB_gelu = [&](const short8 afr[4]) {
        f32x4 accb[8];
        #pragma unroll
        for (int nt = 0; nt < 8; ++nt) accb[nt] = zero4;
        #pragma unroll
        for (int ks = 0; ks < 4; ++ks)
            #pragma unroll
            for (int nt = 0; nt < 8; ++nt) {
                short8 wfr = *(const short8*)(pW + swz(nt * 16 + col, ks * 4 + ak));
                accb[nt] = __builtin_amdgcn_mfma_f32_16x16x32_bf16(wfr, afr[ks], accb[nt], 0, 0, 0);
            }
        #pragma unroll
        for (int nt = 0; nt < 8; ++nt) {
            float y0 = accb[nt][0], y1 = accb[nt][1], y2 = accb[nt][2], y3 = accb[nt][3];
            y0 = 0.5f * y0 * (1.0f + erff(y0 * 0.70710678118654752f));
            y1 = 0.5f * y1 * (1.0f + erff(y1 * 0.70710678118654752f));
            y2 = 0.5f * y2 * (1.0f + erff(y2 * 0.70710678118654752f));
            y3 = 0.5f * y3 * (1.0f + erff(y3 * 0.70710678118654752f));
            unsigned lo = (unsigned)f2bf(y0) | ((unsigned)f2bf(y1) << 16);
            unsigned hi = (unsigned)f2bf(y2) | ((unsigned)f2bf(y3) << 16);
            unsigned long long dv = (unsigned long long)lo | ((unsigned long long)hi << 32);
            *(unsigned long long*)(pXY + swz(arow, nt * 2 + (ak >> 1)) + (ak & 1) * 8) = dv;
        }
    };

    auto w2t_write = [&]() {         // pk regs -> w2t (pW)
        #pragma unroll
        for (int cc = 0; cc < 4; ++cc) {
            int c = colq + cc;
            int rc = e2 * 128 + c;
            int a = (c >> 2) & 3;
            *(uint4*)(pW + (((rc * 2 + 0) ^ a) << 4)) =
                make_uint4(pk[cc][0], pk[cc][1], pk[cc][2], pk[cc][3]);
            *(uint4*)(pW + (((rc * 2 + 1) ^ a) << 4)) =
                make_uint4(pk[cc][4], pk[cc][5], pk[cc][6], pk[cc][7]);
        }
    };

    auto p4 = [&](f32x4 agg[8], int tok0, bool pref) {
        #pragma unroll
        for (int nt = 0; nt < 8; ++nt) agg[nt] = zero4;
        #pragma unroll
        for (int e = 0; e < 8; ++e) {
            if (pref && e == 5)
                load_x(xv2, tok0 + 64);   // tile-2 x prefetch under store phase
            float rwe[4];
            #pragma unroll
            for (int r = 0; r < 4; ++r)
                rwe[r] = pRW[(rb + ak * 4 + r) * 8 + e];
            short8 alo = *(const short8*)(pXY + swz(arow, 2 * e + (ak & 1)));
            short8 af = (ak < 2) ? alo : zfrag;    // K=16 padded to 32
            f32x4 ot[8];
            #pragma unroll
            for (int nt = 0; nt < 8; ++nt) {
                int c = nt * 16 + col;
                int rc = e * 128 + c;
                int a = (c >> 2) & 3;
                short8 blo = *(const short8*)(pW + (((rc * 2 + (ak & 1)) ^ a) << 4));
                short8 bf = (ak < 2) ? blo : zfrag;
                ot[nt] = __builtin_amdgcn_mfma_f32_16x16x32_bf16(af, bf, zero4, 0, 0, 0);
                #pragma unroll
                for (int r = 0; r < 4; ++r)
                    agg[nt][r] += rwe[r] * ot[nt][r];
            }
            // MFMA-layout -> bf16 transpose slice (wave-private rows)
            #pragma unroll
            for (int nt = 0; nt < 8; ++nt)
                #pragma unroll
                for (int r = 0; r < 4; ++r)
                    *(unsigned short*)(pTR + tswz(rb + ak * 4 + r, nt * 16 + col)) = f2bf(ot[nt][r]);
            fence_lds();   // drain DS writes + block compiler reordering (TBAA)
            // read back row-major: 2 full token-expert rows per instruction
            #pragma unroll
            for (int i2 = 0; i2 < 8; ++i2) {
                int row = rb + i2 * 2 + (l >> 5);
                int c0 = (l & 31) * 4;
                unsigned long long raw = *(const unsigned long long*)(pTR + tswz(row, c0));
                unsigned lo = (unsigned)raw, hi = (unsigned)(raw >> 32);
                f32x4 v;
                v[0] = __builtin_bit_cast(float, lo << 16);
                v[1] = __builtin_bit_cast(float, lo & 0xffff0000u);
                v[2] = __builtin_bit_cast(float, hi << 16);
                v[3] = __builtin_bit_cast(float, hi & 0xffff0000u);
                *(f32x4*)(out + O2_OFF + (size_t)(tok0 + row) * 1024 + e * 128 + c0) = v;
            }
            asm volatile("" ::: "memory");   // keep next expert's writes after these reads
        }
    };

    auto epi_agg_write = [&](const f32x4 agg[8]) {
        #pragma unroll
        for (int nt = 0; nt < 8; ++nt) {
            int c = nt * 16 + col;
            #pragma unroll
            for (int r = 0; r < 4; ++r) {
                int row = rb + ak * 4 + r;
                *(float*)(pW + row * 512 + ((c << 2) ^ ((row & 4) << 2))) = agg[nt][r];
            }
        }
    };

    auto epi_read_store = [&](const float4 xv[8], int tok0) {
        #pragma unroll
        for (int s = 0; s < 8; ++s) {
            int row = s * 8 + rsub;
            f32x4 a4 = *(const f32x4*)(pW + row * 512 + ((colq << 2) ^ ((row & 4) << 2)));
            float4 o;
            o.x = xv[s].x + a4[0];
            o.y = xv[s].y + a4[1];
            o.z = xv[s].z + a4[2];
            o.w = xv[s].w + a4[3];
            *(float4*)(out + (size_t)(tok0 + row) * 128 + colq) = o;
        }
    };

    //================ prologue (tile 1) ================
    load_x(xv1, tok0a);
    g4 = *(const float4*)(ln_g + colq);
    b4 = *(const float4*)(ln_b + colq);

    {   // w2 -> pk regs (bf16-packed), persists both tiles
        #pragma unroll
        for (int cc = 0; cc < 4; ++cc)
            #pragma unroll
            for (int q = 0; q < 8; ++q) pk[cc][q] = 0u;
        const float* w2b = w2 + e2 * 2048 + colq;   // w2[e][i][c]
        #pragma unroll
        for (int i = 0; i < 16; ++i) {
            float4 q4 = *(const float4*)(w2b + i * 128);
            unsigned sh = (i & 1) * 16;
            pk[0][i >> 1] |= (unsigned)f2bf(q4.x) << sh;
            pk[1][i >> 1] |= (unsigned)f2bf(q4.y) << sh;
            pk[2][i >> 1] |= (unsigned)f2bf(q4.z) << sh;
            pk[3][i >> 1] |= (unsigned)f2bf(q4.w) << sh;
        }
    }

    w1_loads();
    w1_writes();

    {   // gate weights as A-operand fragments: lane col = expert row (col<8)
        #pragma unroll
        for (int ks = 0; ks < 4; ++ks)
            #pragma unroll
            for (int j = 0; j < 8; ++j) {
                float v = (col < 8) ? gate_w[(32 * ks + 8 * ak + j) * 8 + col] : 0.0f;
                gfr[ks][j] = (short)f2bf(v);
            }
        gb4 = *(const float4*)(gate_b + (ak & 1) * 4);
    }

    ln_to_lds(xv1);
    bar_lds();                       // bar1: xn1 + w1t ready

    //================ tile 1 ================
    short8 afr[4];
    gating(afr, tok0a);
    stageB_gelu(afr);
    bar_lds();                       // bar2: w1t reads done

    w2t_write();
    bar_lds();                       // bar3: w2t + y1 + pRW1 ready

    f32x4 agg[8];
    p4(agg, tok0a, true);            // prefetches xv2 at e==5
    bar_lds();                       // bar4: w2t reads done -> pW free; pXY free

    epi_agg_write(agg);              // agg1 -> pW (f32)
    ln_to_lds(xv2);                  // xn2 -> pXY (overlaps epi writes)
    bar_lds();                       // bar5: agg1 + xn2 ready

    w1_loads();                      // tile-2 w1 reload (L2-hot), into regs
    epi_read_store(xv1, tok0a);      // out0 tile 1
    gating(afr, tok0b);              // gating2 (pXY reads, pRW2/out1 writes)
    bar_lds();                       // bar6: agg1 reads done -> pW free

    w1_writes();                     // w1t for tile 2
    bar_lds();                       // bar7: w1t ready

    stageB_gelu(afr);                // y2 (own-row writes after own afr reads)
    bar_lds();                       // bar8: w1t reads done

    w2t_write();                     // w2t again from pk
    bar_lds();                       // bar9: w2t + y2 + pRW2 ready

    p4(agg, tok0b, false);
    bar_lds();                       // bar10: pW free

    epi_agg_write(agg);
    bar_lds();                       // bar11: agg2 ready

    epi_read_store(xv2, tok0b);      // out0 tile 2
}

extern "C" void kernel_launch(void* const* d_in, const int* in_sizes, int n_in,
                              void* d_out, int out_size, void* d_ws, size_t ws_size,
                              hipStream_t stream) {
    const float* x      = (const float*)d_in[0];
    const float* ln_g   = (const float*)d_in[1];
    const float* ln_b   = (const float*)d_in[2];
    const float* gate_w = (const float*)d_in[3];
    const float* gate_b = (const float*)d_in[4];
    const float* w1     = (const float*)d_in[5];
    const float* w2     = (const float*)d_in[6];
    float* out = (float*)d_out;
    (void)in_sizes; (void)n_in; (void)out_size; (void)d_ws; (void)ws_size;
    moe_fused<<<dim3(512), dim3(256), 0, stream>>>(x, ln_g, ln_b, gate_w, gate_b, w1, w2, out);
}

// Round 6
// 138.788 us; speedup vs baseline: 1.1799x; 1.1799x over previous
//
#include <hip/hip_runtime.h>
#include <math.h>

// Problem: B=8, T=8192, D=128, E=8, I=16.  BT = 65536 tokens.
// Outputs concatenated f32: out0 [BT,128] | out1 [BT,8] | out2 [BT,8,128]
// R6: R5's persistent 2-tile schedule (512 blocks x 128 tokens), but
// straight-line macro implementation -> no alloca demotion / scratch spills.
#define O1_OFF 8388608
#define O2_OFF 8912896

typedef __attribute__((ext_vector_type(8))) short short8;
typedef __attribute__((ext_vector_type(4))) float f32x4;

static __device__ __forceinline__ unsigned short f2bf(float f) {
    unsigned u = __builtin_bit_cast(unsigned, f);
    u = (u + 0x7fffu + ((u >> 16) & 1u)) >> 16;   // RNE
    return (unsigned short)u;
}

// swizzled byte offset inside a [rows][16 x 16B-chunks] LDS region (weights/xn/y)
static __device__ __forceinline__ int swz(int row, int chunk) {
    return row * 256 + ((chunk ^ (row & 7)) << 4);
}

// transpose-region byte offset: [row 0..63][col 0..127] bf16, 256B/row.
static __device__ __forceinline__ int tswz(int row, int col) {
    int chunk = (col >> 3) ^ ((row >> 1) & 6);
    return row * 256 + (chunk << 4) + ((col & 7) << 1);
}

// LDS-only barrier: does NOT drain vmcnt -> global stores stay in flight.
static __device__ __forceinline__ void bar_lds() {
    asm volatile("s_waitcnt lgkmcnt(0)" ::: "memory");
    __builtin_amdgcn_s_barrier();
    asm volatile("" ::: "memory");
}

// within-wave LDS fence: drain DS ops + block compiler (TBAA) reordering
static __device__ __forceinline__ void fence_lds() {
    asm volatile("s_waitcnt lgkmcnt(0)" ::: "memory");
}

//======================= phase macros (R4-verified bodies) =======================
#define LOAD_X(xv, tok0) do {                                                  \
    const float* _xb = x + (size_t)(tok0) * 128;                               \
    _Pragma("unroll")                                                          \
    for (int _s = 0; _s < 8; ++_s)                                             \
        (xv)[_s] = *(const float4*)(_xb + _s * 1024 + t * 4);                  \
} while (0)

#define W1_LOADS() do {                                                        \
    const float* _w1b = w1 + (wp >> 4) * 2048 + (wp & 15);                     \
    _Pragma("unroll")                                                          \
    for (int _cc = 0; _cc < 8; ++_cc) {                                        \
        short8 _v;                                                             \
        _Pragma("unroll")                                                      \
        for (int _j = 0; _j < 8; ++_j)                                         \
            _v[_j] = (short)f2bf(_w1b[(wch * 64 + _cc * 8 + _j) * 16]);        \
        wbuf[_cc] = _v;                                                        \
    }                                                                          \
} while (0)

#define W1_WRITES() do {                                                       \
    _Pragma("unroll")                                                          \
    for (int _cc = 0; _cc < 8; ++_cc)                                          \
        *(short8*)(pW + swz(wp, wch * 8 + _cc)) = wbuf[_cc];                   \
} while (0)

#define LN_TO_LDS(xv) do {                                                     \
    _Pragma("unroll")                                                          \
    for (int _s = 0; _s < 8; ++_s) {                                           \
        float4 _v = (xv)[_s];                                                  \
        float _sm = _v.x + _v.y + _v.z + _v.w;                                 \
        float _sq = _v.x*_v.x + _v.y*_v.y + _v.z*_v.z + _v.w*_v.w;             \
        _Pragma("unroll")                                                      \
        for (int _m = 1; _m < 32; _m <<= 1) {                                  \
            _sm += __shfl_xor(_sm, _m, 64);                                    \
            _sq += __shfl_xor(_sq, _m, 64);                                    \
        }                                                                      \
        float _mu = _sm * (1.0f / 128.0f);                                     \
        float _var = _sq * (1.0f / 128.0f) - _mu * _mu;                        \
        float _rs = rsqrtf(_var + 1e-5f);                                      \
        float _n0 = (_v.x - _mu) * _rs * g4.x + b4.x;                          \
        float _n1 = (_v.y - _mu) * _rs * g4.y + b4.y;                          \
        float _n2 = (_v.z - _mu) * _rs * g4.z + b4.z;                          \
        float _n3 = (_v.w - _mu) * _rs * g4.w + b4.w;                          \
        unsigned _lo = (unsigned)f2bf(_n0) | ((unsigned)f2bf(_n1) << 16);      \
        unsigned _hi = (unsigned)f2bf(_n2) | ((unsigned)f2bf(_n3) << 16);      \
        unsigned long long _dv = (unsigned long long)_lo |                     \
                                 ((unsigned long long)_hi << 32);              \
        int _row = _s * 8 + rsub;                                              \
        *(unsigned long long*)(pXY + swz(_row, colq >> 3) + (colq & 7) * 2) = _dv; \
    }                                                                          \
} while (0)

#define GATING(tok0) do {                                                      \
    _Pragma("unroll")                                                          \
    for (int _ks = 0; _ks < 4; ++_ks)                                          \
        afr[_ks] = *(const short8*)(pXY + swz(arow, _ks * 4 + ak));            \
    f32x4 _accg = zero4;                                                       \
    _Pragma("unroll")                                                          \
    for (int _ks = 0; _ks < 4; ++_ks)                                          \
        _accg = __builtin_amdgcn_mfma_f32_16x16x32_bf16(gfr[_ks], afr[_ks], _accg, 0, 0, 0); \
    const size_t _trow = (size_t)((tok0) + arow);                              \
    float _lg0 = _accg[0] + gb4.x;                                             \
    float _lg1 = _accg[1] + gb4.y;                                             \
    float _lg2 = _accg[2] + gb4.z;                                             \
    float _lg3 = _accg[3] + gb4.w;                                             \
    if (ak < 2) {                                                              \
        f32x4 _lgv = {_lg0, _lg1, _lg2, _lg3};                                 \
        *(f32x4*)(out + O1_OFF + _trow * 8 + ak * 4) = _lgv;                   \
    }                                                                          \
    float _mx = fmaxf(fmaxf(_lg0, _lg1), fmaxf(_lg2, _lg3));                   \
    _mx = fmaxf(_mx, __shfl_xor(_mx, 16, 64));                                 \
    float _e0 = __expf(_lg0 - _mx), _e1 = __expf(_lg1 - _mx);                  \
    float _e2x = __expf(_lg2 - _mx), _e3 = __expf(_lg3 - _mx);                 \
    float _smv = _e0 + _e1 + _e2x + _e3;                                       \
    _smv += __shfl_xor(_smv, 16, 64);                                          \
    float _inv = 1.0f / _smv;                                                  \
    if (ak < 2) {                                                              \
        f32x4 _pv = {_e0 * _inv, _e1 * _inv, _e2x * _inv, _e3 * _inv};         \
        *(f32x4*)(pRW + arow * 8 + ak * 4) = _pv;                              \
    }                                                                          \
} while (0)

#define STAGEB() do {                                                          \
    f32x4 _accb[8];                                                            \
    _Pragma("unroll")                                                          \
    for (int _nt = 0; _nt < 8; ++_nt) _accb[_nt] = zero4;                      \
    _Pragma("unroll")                                                          \
    for (int _ks = 0; _ks < 4; ++_ks) {                                        \
        _Pragma("unroll")                                                      \
        for (int _nt = 0; _nt < 8; ++_nt) {                                    \
            short8 _wfr = *(const short8*)(pW + swz(_nt * 16 + col, _ks * 4 + ak)); \
            _accb[_nt] = __builtin_amdgcn_mfma_f32_16x16x32_bf16(_wfr, afr[_ks], _accb[_nt], 0, 0, 0); \
        }                                                                      \
    }                                                                          \
    _Pragma("unroll")                                                          \
    for (int _nt = 0; _nt < 8; ++_nt) {                                        \
        float _y0 = _accb[_nt][0], _y1 = _accb[_nt][1];                        \
        float _y2 = _accb[_nt][2], _y3 = _accb[_nt][3];                        \
        _y0 = 0.5f * _y0 * (1.0f + erff(_y0 * 0.70710678118654752f));          \
        _y1 = 0.5f * _y1 * (1.0f + erff(_y1 * 0.70710678118654752f));          \
        _y2 = 0.5f * _y2 * (1.0f + erff(_y2 * 0.70710678118654752f));          \
        _y3 = 0.5f * _y3 * (1.0f + erff(_y3 * 0.70710678118654752f));          \
        unsigned _lo = (unsigned)f2bf(_y0) | ((unsigned)f2bf(_y1) << 16);      \
        unsigned _hi = (unsigned)f2bf(_y2) | ((unsigned)f2bf(_y3) << 16);      \
        unsigned long long _dv = (unsigned long long)_lo |                     \
                                 ((unsigned long long)_hi << 32);              \
        *(unsigned long long*)(pXY + swz(arow, _nt * 2 + (ak >> 1)) + (ak & 1) * 8) = _dv; \
    }                                                                          \
} while (0)

#define W2T_WRITE() do {                                                       \
    _Pragma("unroll")                                                          \
    for (int _cc = 0; _cc < 4; ++_cc) {                                        \
        int _c = colq + _cc;                                                   \
        int _rc = e2 * 128 + _c;                                               \
        int _a = (_c >> 2) & 3;                                                \
        *(uint4*)(pW + (((_rc * 2 + 0) ^ _a) << 4)) =                          \
            make_uint4(pk[_cc][0], pk[_cc][1], pk[_cc][2], pk[_cc][3]);        \
        *(uint4*)(pW + (((_rc * 2 + 1) ^ _a) << 4)) =                          \
            make_uint4(pk[_cc][4], pk[_cc][5], pk[_cc][6], pk[_cc][7]);        \
    }                                                                          \
} while (0)

// P4: per-expert GEMM -> bf16 LDS transpose -> full-line out2 stores.
// ot array eliminated: each nt's MFMA result consumed immediately.
#define P4(tok0, PREF) do {                                                    \
    _Pragma("unroll")                                                          \
    for (int _nt = 0; _nt < 8; ++_nt) agg[_nt] = zero4;                        \
    _Pragma("unroll")                                                          \
    for (int _e = 0; _e < 8; ++_e) {                                           \
        if (_e == 5) { PREF; }                                                 \
        float _rwe[4];                                                         \
        _Pragma("unroll")                                                      \
        for (int _r = 0; _r < 4; ++_r)                                         \
            _rwe[_r] = pRW[(rb + ak * 4 + _r) * 8 + _e];                       \
        short8 _alo = *(const short8*)(pXY + swz(arow, 2 * _e + (ak & 1)));    \
        short8 _af = (ak < 2) ? _alo : zfrag;    /* K=16 padded to 32 */       \
        _Pragma("unroll")                                                      \
        for (int _nt = 0; _nt < 8; ++_nt) {                                    \
            int _c = _nt * 16 + col;                                           \
            int _rc = _e * 128 + _c;                                           \
            int _a = (_c >> 2) & 3;                                            \
            short8 _blo = *(const short8*)(pW + (((_rc * 2 + (ak & 1)) ^ _a) << 4)); \
            short8 _bf = (ak < 2) ? _blo : zfrag;                              \
            f32x4 _ot = __builtin_amdgcn_mfma_f32_16x16x32_bf16(_af, _bf, zero4, 0, 0, 0); \
            _Pragma("unroll")                                                  \
            for (int _r = 0; _r < 4; ++_r)                                     \
                agg[_nt][_r] += _rwe[_r] * _ot[_r];                            \
            _Pragma("unroll")                                                  \
            for (int _r = 0; _r < 4; ++_r)                                     \
                *(unsigned short*)(pTR + tswz(rb + ak * 4 + _r, _nt * 16 + col)) = f2bf(_ot[_r]); \
        }                                                                      \
        fence_lds();   /* drain DS writes + block compiler reordering */       \
        _Pragma("unroll")                                                      \
        for (int _i2 = 0; _i2 < 8; ++_i2) {                                    \
            int _row = rb + _i2 * 2 + (l >> 5);                                \
            int _c0 = (l & 31) * 4;                                            \
            unsigned long long _raw = *(const unsigned long long*)(pTR + tswz(_row, _c0)); \
            unsigned _lo = (unsigned)_raw, _hi = (unsigned)(_raw >> 32);       \
            f32x4 _v;                                                          \
            _v[0] = __builtin_bit_cast(float, _lo << 16);                      \
            _v[1] = __builtin_bit_cast(float, _lo & 0xffff0000u);              \
            _v[2] = __builtin_bit_cast(float, _hi << 16);                      \
            _v[3] = __builtin_bit_cast(float, _hi & 0xffff0000u);              \
            *(f32x4*)(out + O2_OFF + (size_t)((tok0) + _row) * 1024 + _e * 128 + _c0) = _v; \
        }                                                                      \
        asm volatile("" ::: "memory");   /* next expert's writes after reads */ \
    }                                                                          \
} while (0)

#define EPI_AGG_WRITE() do {                                                   \
    _Pragma("unroll")                                                          \
    for (int _nt = 0; _nt < 8; ++_nt) {                                        \
        int _c = _nt * 16 + col;                                               \
        _Pragma("unroll")                                                      \
        for (int _r = 0; _r < 4; ++_r) {                                       \
            int _row = rb + ak * 4 + _r;                                       \
            *(float*)(pW + _row * 512 + ((_c << 2) ^ ((_row & 4) << 2))) = agg[_nt][_r]; \
        }                                                                      \
    }                                                                          \
} while (0)

#define EPI_READ_STORE(xv, tok0) do {                                          \
    _Pragma("unroll")                                                          \
    for (int _s = 0; _s < 8; ++_s) {                                           \
        int _row = _s * 8 + rsub;                                              \
        f32x4 _a4 = *(const f32x4*)(pW + _row * 512 + ((colq << 2) ^ ((_row & 4) << 2))); \
        float4 _o;                                                             \
        _o.x = (xv)[_s].x + _a4[0];                                            \
        _o.y = (xv)[_s].y + _a4[1];                                            \
        _o.z = (xv)[_s].z + _a4[2];                                            \
        _o.w = (xv)[_s].w + _a4[3];                                            \
        *(float4*)(out + (size_t)((tok0) + _row) * 128 + colq) = _o;           \
    }                                                                          \
} while (0)

__global__ __launch_bounds__(256, 2) void moe_fused(
    const float* __restrict__ x, const float* __restrict__ ln_g,
    const float* __restrict__ ln_b, const float* __restrict__ gate_w,
    const float* __restrict__ gate_b, const float* __restrict__ w1,
    const float* __restrict__ w2, float* __restrict__ out)
{
    // 66 KB: 2 blocks/CU
    __shared__ __align__(16) char smem[67584];
    char* pXY = smem;                      // 16KB: xn (bf16), then y (bf16)
    char* pW  = smem + 16384;              // 32KB: w1t -> w2t -> agg -> w1t -> ...
    char* pTR = smem + 49152;              // 16KB: bf16 transpose buffer (out2 tiles)
    float* pRW = (float*)(smem + 65536);   // 2KB: routing weights [64][8] f32

    const int t = threadIdx.x;
    const int l = t & 63;
    const int w = t >> 6;
    const int tok0a = blockIdx.x * 128;    // tile 1
    const int tok0b = tok0a + 64;          // tile 2

    const int colq = (t & 31) * 4;   // P0-layout columns
    const int rsub = t >> 5;         // P0-layout row sub-index

    const int rb = w * 16;           // wave's 16 token rows
    const int col = l & 15;          // MFMA n / lane col (token index in tiles)
    const int ak = l >> 4;           // MFMA k-subgroup / token 4-row group
    const int arow = rb + col;
    const int e2 = t >> 5;
    const int wp = t & 127, wch = t >> 7;   // w1 staging indices

    const f32x4 zero4 = {0.f, 0.f, 0.f, 0.f};
    const short8 zfrag = {0, 0, 0, 0, 0, 0, 0, 0};

    float4 xv1[8], xv2[8];           // x tiles in regs
    unsigned pk[4][8];               // w2 bf16-packed, persists both tiles
    short8 wbuf[8];                  // w1 staging slice
    short8 gfr[4];                   // gate fragments, persist
    short8 afr[4];                   // xn fragments (per tile)
    f32x4 agg[8];                    // routing-weighted accumulation
    float4 g4, b4, gb4;

    //================ prologue (tile 1) ================
    LOAD_X(xv1, tok0a);
    g4 = *(const float4*)(ln_g + colq);
    b4 = *(const float4*)(ln_b + colq);

    {   // w2 -> pk regs (bf16-packed), persists both tiles
        #pragma unroll
        for (int cc = 0; cc < 4; ++cc)
            #pragma unroll
            for (int q = 0; q < 8; ++q) pk[cc][q] = 0u;
        const float* w2b = w2 + e2 * 2048 + colq;   // w2[e][i][c]
        #pragma unroll
        for (int i = 0; i < 16; ++i) {
            float4 q4 = *(const float4*)(w2b + i * 128);
            unsigned sh = (i & 1) * 16;
            pk[0][i >> 1] |= (unsigned)f2bf(q4.x) << sh;
            pk[1][i >> 1] |= (unsigned)f2bf(q4.y) << sh;
            pk[2][i >> 1] |= (unsigned)f2bf(q4.z) << sh;
            pk[3][i >> 1] |= (unsigned)f2bf(q4.w) << sh;
        }
    }

    W1_LOADS();
    W1_WRITES();

    {   // gate weights as A-operand fragments: lane col = expert row (col<8)
        #pragma unroll
        for (int ks = 0; ks < 4; ++ks)
            #pragma unroll
            for (int j = 0; j < 8; ++j) {
                float v = (col < 8) ? gate_w[(32 * ks + 8 * ak + j) * 8 + col] : 0.0f;
                gfr[ks][j] = (short)f2bf(v);
            }
        gb4 = *(const float4*)(gate_b + (ak & 1) * 4);
    }

    LN_TO_LDS(xv1);
    bar_lds();                       // bar1: xn1 + w1t ready

    //================ tile 1 ================
    GATING(tok0a);
    STAGEB();
    bar_lds();                       // bar2: w1t reads done

    W2T_WRITE();
    bar_lds();                       // bar3: w2t + y1 + pRW1 ready

    P4(tok0a, LOAD_X(xv2, tok0b));   // prefetches xv2 at e==5
    bar_lds();                       // bar4: w2t reads done -> pW free; pXY free

    EPI_AGG_WRITE();                 // agg1 -> pW (f32)
    LN_TO_LDS(xv2);                  // xn2 -> pXY (overlaps epi writes)
    bar_lds();                       // bar5: agg1 + xn2 ready

    W1_LOADS();                      // tile-2 w1 reload (L2-hot), into regs
    EPI_READ_STORE(xv1, tok0a);      // out0 tile 1
    GATING(tok0b);                   // gating2 (pXY reads, pRW2/out1 writes)
    bar_lds();                       // bar6: agg1 reads done -> pW free

    W1_WRITES();                     // w1t for tile 2
    bar_lds();                       // bar7: w1t ready

    STAGEB();                        // y2
    bar_lds();                       // bar8: w1t reads done

    W2T_WRITE();                     // w2t again from pk
    bar_lds();                       // bar9: w2t + y2 + pRW2 ready

    P4(tok0b, (void)0);
    bar_lds();                       // bar10: pW free

    EPI_AGG_WRITE();
    bar_lds();                       // bar11: agg2 ready

    EPI_READ_STORE(xv2, tok0b);      // out0 tile 2
}

extern "C" void kernel_launch(void* const* d_in, const int* in_sizes, int n_in,
                              void* d_out, int out_size, void* d_ws, size_t ws_size,
                              hipStream_t stream) {
    const float* x      = (const float*)d_in[0];
    const float* ln_g   = (const float*)d_in[1];
    const float* ln_b   = (const float*)d_in[2];
    const float* gate_w = (const float*)d_in[3];
    const float* gate_b = (const float*)d_in[4];
    const float* w1     = (const float*)d_in[5];
    const float* w2     = (const float*)d_in[6];
    float* out = (float*)d_out;
    (void)in_sizes; (void)n_in; (void)out_size; (void)d_ws; (void)ws_size;
    moe_fused<<<dim3(512), dim3(256), 0, stream>>>(x, ln_g, ln_b, gate_w, gate_b, w1, w2, out);
}

// Round 7
// 114.789 us; speedup vs baseline: 1.4265x; 1.2091x over previous
//
#include <hip/hip_runtime.h>
#include <math.h>

// Problem: B=8, T=8192, D=128, E=8, I=16.  BT = 65536 tokens.
// Outputs concatenated f32: out0 [BT,128] | out1 [BT,8] | out2 [BT,8,128]
// R7: 512 blocks x 2 sequential 64-token tiles (one co-resident generation).
// Tile bodies are R4-verbatim; tile 2 reloads weights L2-warm; only gfr and
// the xv2 load issue cross the tile boundary (minimal register pressure).
#define O1_OFF 8388608
#define O2_OFF 8912896

typedef __attribute__((ext_vector_type(8))) short short8;
typedef __attribute__((ext_vector_type(4))) float f32x4;

static __device__ __forceinline__ unsigned short f2bf(float f) {
    unsigned u = __builtin_bit_cast(unsigned, f);
    u = (u + 0x7fffu + ((u >> 16) & 1u)) >> 16;   // RNE
    return (unsigned short)u;
}

// swizzled byte offset inside a [rows][16 x 16B-chunks] LDS region (weights/xn/y)
static __device__ __forceinline__ int swz(int row, int chunk) {
    return row * 256 + ((chunk ^ (row & 7)) << 4);
}

// transpose-region byte offset: [row 0..63][col 0..127] bf16, 256B/row.
static __device__ __forceinline__ int tswz(int row, int col) {
    int chunk = (col >> 3) ^ ((row >> 1) & 6);
    return row * 256 + (chunk << 4) + ((col & 7) << 1);
}

// LDS-only barrier: does NOT drain vmcnt -> global stores/loads stay in flight.
static __device__ __forceinline__ void bar_lds() {
    asm volatile("s_waitcnt lgkmcnt(0)" ::: "memory");
    __builtin_amdgcn_s_barrier();
    asm volatile("" ::: "memory");
}

// within-wave LDS fence: drain DS ops + block compiler (TBAA) reordering
static __device__ __forceinline__ void fence_lds() {
    asm volatile("s_waitcnt lgkmcnt(0)" ::: "memory");
}

//======================= phase macros (R4-verified bodies) =======================
#define LOAD_X(xv, tok0) do {                                                  \
    const float* _xb = x + (size_t)(tok0) * 128;                               \
    _Pragma("unroll")                                                          \
    for (int _s = 0; _s < 8; ++_s)                                             \
        (xv)[_s] = *(const float4*)(_xb + _s * 1024 + t * 4);                  \
} while (0)

// w2 -> pk regs (bf16-packed)
#define W2_PK_LOAD() do {                                                      \
    _Pragma("unroll")                                                          \
    for (int _cc = 0; _cc < 4; ++_cc)                                          \
        _Pragma("unroll")                                                      \
        for (int _q = 0; _q < 8; ++_q) pk[_cc][_q] = 0u;                       \
    const float* _w2b = w2 + e2 * 2048 + colq;   /* w2[e][i][c] */             \
    _Pragma("unroll")                                                          \
    for (int _i = 0; _i < 16; ++_i) {                                          \
        float4 _q4 = *(const float4*)(_w2b + _i * 128);                        \
        unsigned _sh = (_i & 1) * 16;                                          \
        pk[0][_i >> 1] |= (unsigned)f2bf(_q4.x) << _sh;                        \
        pk[1][_i >> 1] |= (unsigned)f2bf(_q4.y) << _sh;                        \
        pk[2][_i >> 1] |= (unsigned)f2bf(_q4.z) << _sh;                        \
        pk[3][_i >> 1] |= (unsigned)f2bf(_q4.w) << _sh;                        \
    }                                                                          \
} while (0)

// w1 global -> f2bf -> w1t LDS (R4 fused staging, no reg buffer)
#define W1_STAGE() do {                                                        \
    const float* _w1b = w1 + (wp >> 4) * 2048 + (wp & 15);   /* w1[e][c][i] */ \
    _Pragma("unroll")                                                          \
    for (int _cc = 0; _cc < 8; ++_cc) {                                        \
        short8 _v;                                                             \
        _Pragma("unroll")                                                      \
        for (int _j = 0; _j < 8; ++_j)                                         \
            _v[_j] = (short)f2bf(_w1b[(wch * 64 + _cc * 8 + _j) * 16]);        \
        *(short8*)(pW + swz(wp, wch * 8 + _cc)) = _v;                          \
    }                                                                          \
} while (0)

#define LN_TO_LDS(xv) do {                                                     \
    _Pragma("unroll")                                                          \
    for (int _s = 0; _s < 8; ++_s) {                                           \
        float4 _v = (xv)[_s];                                                  \
        float _sm = _v.x + _v.y + _v.z + _v.w;                                 \
        float _sq = _v.x*_v.x + _v.y*_v.y + _v.z*_v.z + _v.w*_v.w;             \
        _Pragma("unroll")                                                      \
        for (int _m = 1; _m < 32; _m <<= 1) {                                  \
            _sm += __shfl_xor(_sm, _m, 64);                                    \
            _sq += __shfl_xor(_sq, _m, 64);                                    \
        }                                                                      \
        float _mu = _sm * (1.0f / 128.0f);                                     \
        float _var = _sq * (1.0f / 128.0f) - _mu * _mu;                        \
        float _rs = rsqrtf(_var + 1e-5f);                                      \
        float _n0 = (_v.x - _mu) * _rs * g4.x + b4.x;                          \
        float _n1 = (_v.y - _mu) * _rs * g4.y + b4.y;                          \
        float _n2 = (_v.z - _mu) * _rs * g4.z + b4.z;                          \
        float _n3 = (_v.w - _mu) * _rs * g4.w + b4.w;                          \
        unsigned _lo = (unsigned)f2bf(_n0) | ((unsigned)f2bf(_n1) << 16);      \
        unsigned _hi = (unsigned)f2bf(_n2) | ((unsigned)f2bf(_n3) << 16);      \
        unsigned long long _dv = (unsigned long long)_lo |                     \
                                 ((unsigned long long)_hi << 32);              \
        int _row = _s * 8 + rsub;                                              \
        *(unsigned long long*)(pXY + swz(_row, colq >> 3) + (colq & 7) * 2) = _dv; \
    }                                                                          \
} while (0)

#define GATING(tok0) do {                                                      \
    _Pragma("unroll")                                                          \
    for (int _ks = 0; _ks < 4; ++_ks)                                          \
        afr[_ks] = *(const short8*)(pXY + swz(arow, _ks * 4 + ak));            \
    f32x4 _accg = zero4;                                                       \
    _Pragma("unroll")                                                          \
    for (int _ks = 0; _ks < 4; ++_ks)                                          \
        _accg = __builtin_amdgcn_mfma_f32_16x16x32_bf16(gfr[_ks], afr[_ks], _accg, 0, 0, 0); \
    const size_t _trow = (size_t)((tok0) + arow);                              \
    float _lg0 = _accg[0] + gb4.x;                                             \
    float _lg1 = _accg[1] + gb4.y;                                             \
    float _lg2 = _accg[2] + gb4.z;                                             \
    float _lg3 = _accg[3] + gb4.w;                                             \
    if (ak < 2) {                                                              \
        f32x4 _lgv = {_lg0, _lg1, _lg2, _lg3};                                 \
        *(f32x4*)(out + O1_OFF + _trow * 8 + ak * 4) = _lgv;                   \
    }                                                                          \
    float _mx = fmaxf(fmaxf(_lg0, _lg1), fmaxf(_lg2, _lg3));                   \
    _mx = fmaxf(_mx, __shfl_xor(_mx, 16, 64));                                 \
    float _e0 = __expf(_lg0 - _mx), _e1 = __expf(_lg1 - _mx);                  \
    float _e2x = __expf(_lg2 - _mx), _e3 = __expf(_lg3 - _mx);                 \
    float _smv = _e0 + _e1 + _e2x + _e3;                                       \
    _smv += __shfl_xor(_smv, 16, 64);                                          \
    float _inv = 1.0f / _smv;                                                  \
    if (ak < 2) {                                                              \
        f32x4 _pv = {_e0 * _inv, _e1 * _inv, _e2x * _inv, _e3 * _inv};         \
        *(f32x4*)(pRW + arow * 8 + ak * 4) = _pv;                              \
    }                                                                          \
} while (0)

#define STAGEB() do {                                                          \
    f32x4 _accb[8];                                                            \
    _Pragma("unroll")                                                          \
    for (int _nt = 0; _nt < 8; ++_nt) _accb[_nt] = zero4;                      \
    _Pragma("unroll")                                                          \
    for (int _ks = 0; _ks < 4; ++_ks) {                                        \
        _Pragma("unroll")                                                      \
        for (int _nt = 0; _nt < 8; ++_nt) {                                    \
            short8 _wfr = *(const short8*)(pW + swz(_nt * 16 + col, _ks * 4 + ak)); \
            _accb[_nt] = __builtin_amdgcn_mfma_f32_16x16x32_bf16(_wfr, afr[_ks], _accb[_nt], 0, 0, 0); \
        }                                                                      \
    }                                                                          \
    _Pragma("unroll")                                                          \
    for (int _nt = 0; _nt < 8; ++_nt) {                                        \
        float _y0 = _accb[_nt][0], _y1 = _accb[_nt][1];                        \
        float _y2 = _accb[_nt][2], _y3 = _accb[_nt][3];                        \
        _y0 = 0.5f * _y0 * (1.0f + erff(_y0 * 0.70710678118654752f));          \
        _y1 = 0.5f * _y1 * (1.0f + erff(_y1 * 0.70710678118654752f));          \
        _y2 = 0.5f * _y2 * (1.0f + erff(_y2 * 0.70710678118654752f));          \
        _y3 = 0.5f * _y3 * (1.0f + erff(_y3 * 0.70710678118654752f));          \
        unsigned _lo = (unsigned)f2bf(_y0) | ((unsigned)f2bf(_y1) << 16);      \
        unsigned _hi = (unsigned)f2bf(_y2) | ((unsigned)f2bf(_y3) << 16);      \
        unsigned long long _dv = (unsigned long long)_lo |                     \
                                 ((unsigned long long)_hi << 32);              \
        *(unsigned long long*)(pXY + swz(arow, _nt * 2 + (ak >> 1)) + (ak & 1) * 8) = _dv; \
    }                                                                          \
} while (0)

#define W2T_WRITE() do {                                                       \
    _Pragma("unroll")                                                          \
    for (int _cc = 0; _cc < 4; ++_cc) {                                        \
        int _c = colq + _cc;                                                   \
        int _rc = e2 * 128 + _c;                                               \
        int _a = (_c >> 2) & 3;                                                \
        *(uint4*)(pW + (((_rc * 2 + 0) ^ _a) << 4)) =                          \
            make_uint4(pk[_cc][0], pk[_cc][1], pk[_cc][2], pk[_cc][3]);        \
        *(uint4*)(pW + (((_rc * 2 + 1) ^ _a) << 4)) =                          \
            make_uint4(pk[_cc][4], pk[_cc][5], pk[_cc][6], pk[_cc][7]);        \
    }                                                                          \
} while (0)

// P4: per-expert GEMM -> bf16 LDS transpose -> full-line out2 stores (R4 exact)
#define P4(tok0) do {                                                          \
    _Pragma("unroll")                                                          \
    for (int _nt = 0; _nt < 8; ++_nt) agg[_nt] = zero4;                        \
    _Pragma("unroll")                                                          \
    for (int _e = 0; _e < 8; ++_e) {                                           \
        float _rwe[4];                                                         \
        _Pragma("unroll")                                                      \
        for (int _r = 0; _r < 4; ++_r)                                         \
            _rwe[_r] = pRW[(rb + ak * 4 + _r) * 8 + _e];                       \
        short8 _alo = *(const short8*)(pXY + swz(arow, 2 * _e + (ak & 1)));    \
        short8 _af = (ak < 2) ? _alo : zfrag;    /* K=16 padded to 32 */       \
        f32x4 _ot[8];                                                          \
        _Pragma("unroll")                                                      \
        for (int _nt = 0; _nt < 8; ++_nt) {                                    \
            int _c = _nt * 16 + col;                                           \
            int _rc = _e * 128 + _c;                                           \
            int _a = (_c >> 2) & 3;                                            \
            short8 _blo = *(const short8*)(pW + (((_rc * 2 + (ak & 1)) ^ _a) << 4)); \
            short8 _bf = (ak < 2) ? _blo : zfrag;                              \
            _ot[_nt] = __builtin_amdgcn_mfma_f32_16x16x32_bf16(_af, _bf, zero4, 0, 0, 0); \
            _Pragma("unroll")                                                  \
            for (int _r = 0; _r < 4; ++_r)                                     \
                agg[_nt][_r] += _rwe[_r] * _ot[_nt][_r];                       \
        }                                                                      \
        _Pragma("unroll")                                                      \
        for (int _nt = 0; _nt < 8; ++_nt)                                      \
            _Pragma("unroll")                                                  \
            for (int _r = 0; _r < 4; ++_r)                                     \
                *(unsigned short*)(pTR + tswz(rb + ak * 4 + _r, _nt * 16 + col)) = f2bf(_ot[_nt][_r]); \
        fence_lds();   /* drain DS writes + block compiler reordering */       \
        _Pragma("unroll")                                                      \
        for (int _i2 = 0; _i2 < 8; ++_i2) {                                    \
            int _row = rb + _i2 * 2 + (l >> 5);                                \
            int _c0 = (l & 31) * 4;                                            \
            unsigned long long _raw = *(const unsigned long long*)(pTR + tswz(_row, _c0)); \
            unsigned _lo = (unsigned)_raw, _hi = (unsigned)(_raw >> 32);       \
            f32x4 _v;                                                          \
            _v[0] = __builtin_bit_cast(float, _lo << 16);                      \
            _v[1] = __builtin_bit_cast(float, _lo & 0xffff0000u);              \
            _v[2] = __builtin_bit_cast(float, _hi << 16);                      \
            _v[3] = __builtin_bit_cast(float, _hi & 0xffff0000u);              \
            *(f32x4*)(out + O2_OFF + (size_t)((tok0) + _row) * 1024 + _e * 128 + _c0) = _v; \
        }                                                                      \
        asm volatile("" ::: "memory");   /* next expert's writes after reads */ \
    }                                                                          \
} while (0)

#define EPI_AGG_WRITE() do {                                                   \
    _Pragma("unroll")                                                          \
    for (int _nt = 0; _nt < 8; ++_nt) {                                        \
        int _c = _nt * 16 + col;                                               \
        _Pragma("unroll")                                                      \
        for (int _r = 0; _r < 4; ++_r) {                                       \
            int _row = rb + ak * 4 + _r;                                       \
            *(float*)(pW + _row * 512 + ((_c << 2) ^ ((_row & 4) << 2))) = agg[_nt][_r]; \
        }                                                                      \
    }                                                                          \
} while (0)

#define EPI_READ_STORE(xv, tok0) do {                                          \
    _Pragma("unroll")                                                          \
    for (int _s = 0; _s < 8; ++_s) {                                           \
        int _row = _s * 8 + rsub;                                              \
        f32x4 _a4 = *(const f32x4*)(pW + _row * 512 + ((colq << 2) ^ ((_row & 4) << 2))); \
        float4 _o;                                                             \
        _o.x = (xv)[_s].x + _a4[0];                                            \
        _o.y = (xv)[_s].y + _a4[1];                                            \
        _o.z = (xv)[_s].z + _a4[2];                                            \
        _o.w = (xv)[_s].w + _a4[3];                                            \
        *(float4*)(out + (size_t)((tok0) + _row) * 128 + colq) = _o;           \
    }                                                                          \
} while (0)

__global__ __launch_bounds__(256, 2) void moe_fused(
    const float* __restrict__ x, const float* __restrict__ ln_g,
    const float* __restrict__ ln_b, const float* __restrict__ gate_w,
    const float* __restrict__ gate_b, const float* __restrict__ w1,
    const float* __restrict__ w2, float* __restrict__ out)
{
    // 66 KB: 2 blocks/CU
    __shared__ __align__(16) char smem[67584];
    char* pXY = smem;                      // 16KB: xn (bf16), then y (bf16)
    char* pW  = smem + 16384;              // 32KB: w1t -> w2t -> agg -> w1t ...
    char* pTR = smem + 49152;              // 16KB: bf16 transpose buffer (out2 tiles)
    float* pRW = (float*)(smem + 65536);   // 2KB: routing weights [64][8] f32

    const int t = threadIdx.x;
    const int l = t & 63;
    const int w = t >> 6;
    const int tok0a = blockIdx.x * 128;    // tile 1
    const int tok0b = tok0a + 64;          // tile 2

    const int colq = (t & 31) * 4;   // P0-layout columns
    const int rsub = t >> 5;         // P0-layout row sub-index

    const int rb = w * 16;           // wave's 16 token rows
    const int col = l & 15;          // MFMA n / lane col (token index in tiles)
    const int ak = l >> 4;           // MFMA k-subgroup / token 4-row group
    const int arow = rb + col;
    const int e2 = t >> 5;
    const int wp = t & 127, wch = t >> 7;   // w1 staging indices

    const f32x4 zero4 = {0.f, 0.f, 0.f, 0.f};
    const short8 zfrag = {0, 0, 0, 0, 0, 0, 0, 0};

    float4 xv1[8], xv2[8];           // x tiles (xv2 born in bar4-5 window)
    unsigned pk[4][8];               // w2 bf16-packed (reloaded per tile, L2-warm)
    short8 gfr[4];                   // gate fragments, persist both tiles
    short8 afr[4];                   // xn fragments (per tile)
    f32x4 agg[8];                    // routing-weighted accumulation
    float4 g4, b4, gb4;

    //================ prologue (tile 1) — R4 verbatim ================
    LOAD_X(xv1, tok0a);
    g4 = *(const float4*)(ln_g + colq);
    b4 = *(const float4*)(ln_b + colq);

    W2_PK_LOAD();
    W1_STAGE();

    {   // gate weights as A-operand fragments: lane col = expert row (col<8)
        #pragma unroll
        for (int ks = 0; ks < 4; ++ks)
            #pragma unroll
            for (int j = 0; j < 8; ++j) {
                float v = (col < 8) ? gate_w[(32 * ks + 8 * ak + j) * 8 + col] : 0.0f;
                gfr[ks][j] = (short)f2bf(v);
            }
        gb4 = *(const float4*)(gate_b + (ak & 1) * 4);
    }

    LN_TO_LDS(xv1);
    bar_lds();                       // bar1: xn1 + w1t ready

    //================ tile 1 — R4 verbatim ================
    GATING(tok0a);
    STAGEB();
    bar_lds();                       // bar2: w1t reads done

    W2T_WRITE();
    bar_lds();                       // bar3: w2t + y1 + pRW1 ready

    P4(tok0a);
    bar_lds();                       // bar4: w2t/pRW/y reads done -> pW, pXY free

    //================ tile-1 epilogue ∥ tile-2 front-end ================
    LOAD_X(xv2, tok0b);              // issue early; latency hides under epilogue
    EPI_AGG_WRITE();                 // agg1 -> pW (f32)
    W2_PK_LOAD();                    // L2-warm w2 re-pack
    bar_lds();                       // bar5: agg1 tile ready

    EPI_READ_STORE(xv1, tok0a);      // out0 tile 1 (reads pW agg1)
    LN_TO_LDS(xv2);                  // xn2 -> pXY (y1 dead; block-wide scatter)
    bar_lds();                       // bar6: agg1 reads done + xn2 ready

    GATING(tok0b);                   // afr2 from xn2; out1 + pRW2 writes
    W1_STAGE();                      // w1t2 -> pW (L2-warm; agg1 reads done)
    bar_lds();                       // bar7: w1t2 + pRW2 ready

    STAGEB();                        // y2 (own-row overwrite of xn2 after afr2 read)
    bar_lds();                       // bar8: w1t2 reads done -> pW free

    W2T_WRITE();                     // w2t2 from pk
    bar_lds();                       // bar9: w2t2 + y2 ready

    P4(tok0b);
    bar_lds();                       // bar10: pW free

    EPI_AGG_WRITE();
    bar_lds();                       // bar11: agg2 ready

    EPI_READ_STORE(xv2, tok0b);      // out0 tile 2
}

extern "C" void kernel_launch(void* const* d_in, const int* in_sizes, int n_in,
                              void* d_out, int out_size, void* d_ws, size_t ws_size,
                              hipStream_t stream) {
    const float* x      = (const float*)d_in[0];
    const float* ln_g   = (const float*)d_in[1];
    const float* ln_b   = (const float*)d_in[2];
    const float* gate_w = (const float*)d_in[3];
    const float* gate_b = (const float*)d_in[4];
    const float* w1     = (const float*)d_in[5];
    const float* w2     = (const float*)d_in[6];
    float* out = (float*)d_out;
    (void)in_sizes; (void)n_in; (void)out_size; (void)d_ws; (void)ws_size;
    moe_fused<<<dim3(512), dim3(256), 0, stream>>>(x, ln_g, ln_b, gate_w, gate_b, w1, w2, out);
}

// Round 8
// 78.864 us; speedup vs baseline: 2.0764x; 1.4555x over previous
//
#include <hip/hip_runtime.h>
#include <math.h>

// Problem: B=8, T=8192, D=128, E=8, I=16.  BT = 65536 tokens.
// Outputs concatenated f32: out0 [BT,128] | out1 [BT,8] | out2 [BT,8,128]
// R8: exact R4 structure (measured 80.9 us) + nontemporal hints on the
// full-line out2/out0 stores (clean A/B; R1's NT test was confounded).
#define O1_OFF 8388608
#define O2_OFF 8912896

typedef __attribute__((ext_vector_type(8))) short short8;
typedef __attribute__((ext_vector_type(4))) float f32x4;

static __device__ __forceinline__ unsigned short f2bf(float f) {
    unsigned u = __builtin_bit_cast(unsigned, f);
    u = (u + 0x7fffu + ((u >> 16) & 1u)) >> 16;   // RNE
    return (unsigned short)u;
}

// swizzled byte offset inside a [rows][16 x 16B-chunks] LDS region (weights/xn/y)
static __device__ __forceinline__ int swz(int row, int chunk) {
    return row * 256 + ((chunk ^ (row & 7)) << 4);
}

// transpose-region byte offset: [row 0..63][col 0..127] bf16, 256B/row.
static __device__ __forceinline__ int tswz(int row, int col) {
    int chunk = (col >> 3) ^ ((row >> 1) & 6);
    return row * 256 + (chunk << 4) + ((col & 7) << 1);
}

// LDS-only barrier: does NOT drain vmcnt -> global stores stay in flight.
static __device__ __forceinline__ void bar_lds() {
    asm volatile("s_waitcnt lgkmcnt(0)" ::: "memory");
    __builtin_amdgcn_s_barrier();
    asm volatile("" ::: "memory");
}

// within-wave LDS fence: drain DS ops + block compiler (TBAA) reordering
static __device__ __forceinline__ void fence_lds() {
    asm volatile("s_waitcnt lgkmcnt(0)" ::: "memory");
}

__global__ __launch_bounds__(256, 2) void moe_fused(
    const float* __restrict__ x, const float* __restrict__ ln_g,
    const float* __restrict__ ln_b, const float* __restrict__ gate_w,
    const float* __restrict__ gate_b, const float* __restrict__ w1,
    const float* __restrict__ w2, float* __restrict__ out)
{
    // 66 KB: 2 blocks/CU
    __shared__ __align__(16) char smem[67584];
    char* pXY = smem;                      // 16KB: xn (bf16), then y (bf16)
    char* pW  = smem + 16384;              // 32KB: w1t, then w2t, then agg f32
    char* pTR = smem + 49152;              // 16KB: bf16 transpose buffer (out2 tiles)
    float* pRW = (float*)(smem + 65536);   // 2KB: routing weights [64][8] f32

    const int t = threadIdx.x;
    const int l = t & 63;
    const int w = t >> 6;
    const int tok0 = blockIdx.x * 64;

    const int colq = (t & 31) * 4;   // P0-layout columns
    const int rsub = t >> 5;         // P0-layout row sub-index

    const int rb = w * 16;           // wave's 16 token rows
    const int col = l & 15;          // MFMA n / lane col (token index in tiles)
    const int ak = l >> 4;           // MFMA k-subgroup / token 4-row group
    const int arow = rb + col;

    //---------------- P0: global loads + staging ----------------
    float4 xv[8];                    // x tile, held in regs to the end
    {
        const float* xb = x + (size_t)tok0 * 128;
        #pragma unroll
        for (int s = 0; s < 8; ++s)
            xv[s] = *(const float4*)(xb + s * 1024 + t * 4);
    }
    float4 g4 = *(const float4*)(ln_g + colq);
    float4 b4 = *(const float4*)(ln_b + colq);

    // w2 staged in registers (bf16-packed) until w1t region is free (bar2)
    const int e2 = t >> 5;
    unsigned pk[4][8];
    {
        #pragma unroll
        for (int cc = 0; cc < 4; ++cc)
            #pragma unroll
            for (int q = 0; q < 8; ++q) pk[cc][q] = 0u;
        const float* w2b = w2 + e2 * 2048 + colq;   // w2[e][i][c]
        #pragma unroll
        for (int i = 0; i < 16; ++i) {
            float4 q4 = *(const float4*)(w2b + i * 128);
            unsigned sh = (i & 1) * 16;
            pk[0][i >> 1] |= (unsigned)f2bf(q4.x) << sh;
            pk[1][i >> 1] |= (unsigned)f2bf(q4.y) << sh;
            pk[2][i >> 1] |= (unsigned)f2bf(q4.z) << sh;
            pk[3][i >> 1] |= (unsigned)f2bf(q4.w) << sh;
        }
    }

    // w1 -> w1t[p][c] bf16 (p = e*16+i), swizzled
    {
        const int p = t & 127, ch = t >> 7;
        const float* w1b = w1 + (p >> 4) * 2048 + (p & 15);   // w1[e][c][i]
        #pragma unroll
        for (int cc = 0; cc < 8; ++cc) {
            short8 v;
            #pragma unroll
            for (int j = 0; j < 8; ++j)
                v[j] = (short)f2bf(w1b[(ch * 64 + cc * 8 + j) * 16]);
            *(short8*)(pW + swz(p, ch * 8 + cc)) = v;
        }
    }

    // gate weights as A-operand fragments: lane col = expert row (col<8), k = c
    short8 gfr[4];
    float4 gb4;
    {
        #pragma unroll
        for (int ks = 0; ks < 4; ++ks)
            #pragma unroll
            for (int j = 0; j < 8; ++j) {
                float v = (col < 8) ? gate_w[(32 * ks + 8 * ak + j) * 8 + col] : 0.0f;
                gfr[ks][j] = (short)f2bf(v);
            }
        gb4 = *(const float4*)(gate_b + (ak & 1) * 4);
    }

    //---------------- LN in registers, xn -> LDS ----------------
    #pragma unroll
    for (int s = 0; s < 8; ++s) {
        float4 v = xv[s];
        float sm = v.x + v.y + v.z + v.w;
        float sq = v.x*v.x + v.y*v.y + v.z*v.z + v.w*v.w;
        #pragma unroll
        for (int m = 1; m < 32; m <<= 1) {
            sm += __shfl_xor(sm, m, 64);
            sq += __shfl_xor(sq, m, 64);
        }
        float mu = sm * (1.0f / 128.0f);
        float var = sq * (1.0f / 128.0f) - mu * mu;
        float rs = rsqrtf(var + 1e-5f);
        float n0 = (v.x - mu) * rs * g4.x + b4.x;
        float n1 = (v.y - mu) * rs * g4.y + b4.y;
        float n2 = (v.z - mu) * rs * g4.z + b4.z;
        float n3 = (v.w - mu) * rs * g4.w + b4.w;
        unsigned lo = (unsigned)f2bf(n0) | ((unsigned)f2bf(n1) << 16);
        unsigned hi = (unsigned)f2bf(n2) | ((unsigned)f2bf(n3) << 16);
        unsigned long long dvv = (unsigned long long)lo | ((unsigned long long)hi << 32);
        int row = s * 8 + rsub;
        *(unsigned long long*)(pXY + swz(row, colq >> 3) + (colq & 7) * 2) = dvv;
    }

    bar_lds();   // bar1: xn + w1t ready

    const f32x4 zero4 = {0.f, 0.f, 0.f, 0.f};
    const short8 zfrag = {0, 0, 0, 0, 0, 0, 0, 0};

    // xn fragments (lane col = token within wave tile, k = c)
    short8 afr[4];
    #pragma unroll
    for (int ks = 0; ks < 4; ++ks)
        afr[ks] = *(const short8*)(pXY + swz(arow, ks * 4 + ak));

    //---------------- gating (swapped): D[e][token] ----------------
    f32x4 accg = zero4;
    #pragma unroll
    for (int ks = 0; ks < 4; ++ks)
        accg = __builtin_amdgcn_mfma_f32_16x16x32_bf16(gfr[ks], afr[ks], accg, 0, 0, 0);

    const size_t trow = (size_t)(tok0 + arow);
    {
        // lane holds logits for token trow, experts e = ak*4 + r (valid ak<2)
        float lg0 = accg[0] + gb4.x;
        float lg1 = accg[1] + gb4.y;
        float lg2 = accg[2] + gb4.z;
        float lg3 = accg[3] + gb4.w;
        if (ak < 2) {
            f32x4 lgv = {lg0, lg1, lg2, lg3};
            *(f32x4*)(out + O1_OFF + trow * 8 + ak * 4) = lgv;
        }
        float mx = fmaxf(fmaxf(lg0, lg1), fmaxf(lg2, lg3));
        mx = fmaxf(mx, __shfl_xor(mx, 16, 64));
        float ex0 = __expf(lg0 - mx), ex1 = __expf(lg1 - mx);
        float ex2 = __expf(lg2 - mx), ex3 = __expf(lg3 - mx);
        float sm = ex0 + ex1 + ex2 + ex3;
        sm += __shfl_xor(sm, 16, 64);
        float inv = 1.0f / sm;
        if (ak < 2) {
            f32x4 pv = {ex0 * inv, ex1 * inv, ex2 * inv, ex3 * inv};
            *(f32x4*)(pRW + arow * 8 + ak * 4) = pv;
        }
    }

    //---------------- stage B (swapped): y^T per token in-lane ----------------
    f32x4 accb[8];
    #pragma unroll
    for (int nt = 0; nt < 8; ++nt) accb[nt] = zero4;
    #pragma unroll
    for (int ks = 0; ks < 4; ++ks)
        #pragma unroll
        for (int nt = 0; nt < 8; ++nt) {
            short8 wfr = *(const short8*)(pW + swz(nt * 16 + col, ks * 4 + ak));
            accb[nt] = __builtin_amdgcn_mfma_f32_16x16x32_bf16(wfr, afr[ks], accb[nt], 0, 0, 0);
        }

    // exact-erf GELU; lane holds token arow, ei = nt*16 + ak*4 + r -> 8B packed write
    #pragma unroll
    for (int nt = 0; nt < 8; ++nt) {
        float y0 = accb[nt][0], y1 = accb[nt][1], y2 = accb[nt][2], y3 = accb[nt][3];
        y0 = 0.5f * y0 * (1.0f + erff(y0 * 0.70710678118654752f));
        y1 = 0.5f * y1 * (1.0f + erff(y1 * 0.70710678118654752f));
        y2 = 0.5f * y2 * (1.0f + erff(y2 * 0.70710678118654752f));
        y3 = 0.5f * y3 * (1.0f + erff(y3 * 0.70710678118654752f));
        unsigned lo = (unsigned)f2bf(y0) | ((unsigned)f2bf(y1) << 16);
        unsigned hi = (unsigned)f2bf(y2) | ((unsigned)f2bf(y3) << 16);
        unsigned long long dv = (unsigned long long)lo | ((unsigned long long)hi << 32);
        *(unsigned long long*)(pXY + swz(arow, nt * 2 + (ak >> 1)) + (ak & 1) * 8) = dv;
    }

    bar_lds();   // bar2: all stage-B w1t reads done -> w1t region reusable

    // staged w2 -> w2t[(e,c)][i] bf16, chunk' = (rc*2+half) ^ ((c>>2)&3)
    #pragma unroll
    for (int cc = 0; cc < 4; ++cc) {
        int c = colq + cc;
        int rc = e2 * 128 + c;
        int a = (c >> 2) & 3;
        *(uint4*)(pW + (((rc * 2 + 0) ^ a) << 4)) =
            make_uint4(pk[cc][0], pk[cc][1], pk[cc][2], pk[cc][3]);
        *(uint4*)(pW + (((rc * 2 + 1) ^ a) << 4)) =
            make_uint4(pk[cc][4], pk[cc][5], pk[cc][6], pk[cc][7]);
    }

    bar_lds();   // bar3: w2t + y + pRW ready

    //---------------- P4: per-expert GEMM -> LDS transpose -> full-line stores ---
    f32x4 agg[8];
    #pragma unroll
    for (int nt = 0; nt < 8; ++nt) agg[nt] = zero4;

    #pragma unroll
    for (int e = 0; e < 8; ++e) {
        float rwe[4];
        #pragma unroll
        for (int r = 0; r < 4; ++r)
            rwe[r] = pRW[(rb + ak * 4 + r) * 8 + e];
        short8 alo = *(const short8*)(pXY + swz(arow, 2 * e + (ak & 1)));
        short8 af = (ak < 2) ? alo : zfrag;    // K=16 padded to 32
        f32x4 ot[8];
        #pragma unroll
        for (int nt = 0; nt < 8; ++nt) {
            int c = nt * 16 + col;
            int rc = e * 128 + c;
            int a = (c >> 2) & 3;
            short8 blo = *(const short8*)(pW + (((rc * 2 + (ak & 1)) ^ a) << 4));
            short8 bf = (ak < 2) ? blo : zfrag;
            ot[nt] = __builtin_amdgcn_mfma_f32_16x16x32_bf16(af, bf, zero4, 0, 0, 0);
            #pragma unroll
            for (int r = 0; r < 4; ++r)
                agg[nt][r] += rwe[r] * ot[nt][r];
        }
        // MFMA-layout -> bf16 transpose slice (wave-private rows)
        #pragma unroll
        for (int nt = 0; nt < 8; ++nt)
            #pragma unroll
            for (int r = 0; r < 4; ++r)
                *(unsigned short*)(pTR + tswz(rb + ak * 4 + r, nt * 16 + col)) = f2bf(ot[nt][r]);
        fence_lds();   // drain DS writes + block compiler reordering (TBAA)
        // read back row-major: 2 full token-expert rows per instruction
        #pragma unroll
        for (int i2 = 0; i2 < 8; ++i2) {
            int row = rb + i2 * 2 + (l >> 5);
            int c0 = (l & 31) * 4;
            unsigned long long raw = *(const unsigned long long*)(pTR + tswz(row, c0));
            unsigned lo = (unsigned)raw, hi = (unsigned)(raw >> 32);
            f32x4 v;
            v[0] = __builtin_bit_cast(float, lo << 16);
            v[1] = __builtin_bit_cast(float, lo & 0xffff0000u);
            v[2] = __builtin_bit_cast(float, hi << 16);
            v[3] = __builtin_bit_cast(float, hi & 0xffff0000u);
            __builtin_nontemporal_store(v,
                (f32x4*)(out + O2_OFF + (size_t)(tok0 + row) * 1024 + e * 128 + c0));
        }
        asm volatile("" ::: "memory");   // keep next expert's writes after these reads
    }

    bar_lds();   // bar4: all waves' w2t reads done -> pW reusable for agg (f32)

    //---------------- epilogue: f32 agg through pW (R0-verified scheme) ----------
    #pragma unroll
    for (int nt = 0; nt < 8; ++nt) {
        int c = nt * 16 + col;
        #pragma unroll
        for (int r = 0; r < 4; ++r) {
            int row = rb + ak * 4 + r;
            *(float*)(pW + row * 512 + ((c << 2) ^ ((row & 4) << 2))) = agg[nt][r];
        }
    }

    bar_lds();   // bar5: agg tile ready in P0 layout

    #pragma unroll
    for (int s = 0; s < 8; ++s) {
        int row = s * 8 + rsub;
        f32x4 a4 = *(const f32x4*)(pW + row * 512 + ((colq << 2) ^ ((row & 4) << 2)));
        f32x4 o;
        o[0] = xv[s].x + a4[0];
        o[1] = xv[s].y + a4[1];
        o[2] = xv[s].z + a4[2];
        o[3] = xv[s].w + a4[3];
        __builtin_nontemporal_store(o,
            (f32x4*)(out + (size_t)(tok0 + row) * 128 + colq));
    }
}

extern "C" void kernel_launch(void* const* d_in, const int* in_sizes, int n_in,
                              void* d_out, int out_size, void* d_ws, size_t ws_size,
                              hipStream_t stream) {
    const float* x      = (const float*)d_in[0];
    const float* ln_g   = (const float*)d_in[1];
    const float* ln_b   = (const float*)d_in[2];
    const float* gate_w = (const float*)d_in[3];
    const float* gate_b = (const float*)d_in[4];
    const float* w1     = (const float*)d_in[5];
    const float* w2     = (const float*)d_in[6];
    float* out = (float*)d_out;
    (void)in_sizes; (void)n_in; (void)out_size; (void)d_ws; (void)ws_size;
    moe_fused<<<dim3(1024), dim3(256), 0, stream>>>(x, ln_g, ln_b, gate_w, gate_b, w1, w2, out);
}

// Round 9
// 78.385 us; speedup vs baseline: 2.0891x; 1.0061x over previous
//
#include <hip/hip_runtime.h>
#include <math.h>

// Problem: B=8, T=8192, D=128, E=8, I=16.  BT = 65536 tokens.
// Outputs concatenated f32: out0 [BT,128] | out1 [BT,8] | out2 [BT,8,128]
// R9: R8 structure (78.9 us) + weight-prep kernel: w1/w2/gate converted to
// bf16 LDS-layout images in d_ws once; main-kernel prologue becomes linear
// 16B copies (no strided scalar loads, no f2bf on weights, pk regs deleted).
#define O1_OFF 8388608
#define O2_OFF 8912896

// d_ws layout: [0,32768) w1t image | [32768,65536) w2t image | [65536,69632) gfr image
#define WS_W2T 32768
#define WS_GFR 65536

typedef __attribute__((ext_vector_type(8))) short short8;
typedef __attribute__((ext_vector_type(4))) float f32x4;

static __device__ __forceinline__ unsigned short f2bf(float f) {
    unsigned u = __builtin_bit_cast(unsigned, f);
    u = (u + 0x7fffu + ((u >> 16) & 1u)) >> 16;   // RNE
    return (unsigned short)u;
}

// swizzled byte offset inside a [rows][16 x 16B-chunks] LDS region (weights/xn/y)
static __device__ __forceinline__ int swz(int row, int chunk) {
    return row * 256 + ((chunk ^ (row & 7)) << 4);
}

// transpose-region byte offset: [row 0..63][col 0..127] bf16, 256B/row.
static __device__ __forceinline__ int tswz(int row, int col) {
    int chunk = (col >> 3) ^ ((row >> 1) & 6);
    return row * 256 + (chunk << 4) + ((col & 7) << 1);
}

// LDS-only barrier: does NOT drain vmcnt -> global stores stay in flight.
static __device__ __forceinline__ void bar_lds() {
    asm volatile("s_waitcnt lgkmcnt(0)" ::: "memory");
    __builtin_amdgcn_s_barrier();
    asm volatile("" ::: "memory");
}

// within-wave LDS fence: drain DS ops + block compiler (TBAA) reordering
static __device__ __forceinline__ void fence_lds() {
    asm volatile("s_waitcnt lgkmcnt(0)" ::: "memory");
}

//=============== prep kernel: weights -> bf16 LDS-layout images in ws ===========
__global__ __launch_bounds__(256) void moe_prep(
    const float* __restrict__ gate_w, const float* __restrict__ w1,
    const float* __restrict__ w2, char* __restrict__ ws)
{
    const int t = threadIdx.x;
    const int b = blockIdx.x;
    if (b < 4) {
        // w1t image: p = e*16+i rows, swizzled; block b covers cc = 2b, 2b+1
        const int p = t & 127, ch = t >> 7;
        const float* w1b = w1 + (p >> 4) * 2048 + (p & 15);   // w1[e][c][i]
        #pragma unroll
        for (int q = 0; q < 2; ++q) {
            int cc = 2 * b + q;
            short8 v;
            #pragma unroll
            for (int j = 0; j < 8; ++j)
                v[j] = (short)f2bf(w1b[(ch * 64 + cc * 8 + j) * 16]);
            *(short8*)(ws + swz(p, ch * 8 + cc)) = v;
        }
        // gfr image: lane l holds 4 short8 A-fragments of gate_w (col<8 rows)
        if (b == 0 && t < 64) {
            const int col = t & 15, ak = t >> 4;
            #pragma unroll
            for (int ks = 0; ks < 4; ++ks) {
                short8 v;
                #pragma unroll
                for (int j = 0; j < 8; ++j) {
                    float f = (col < 8) ? gate_w[(32 * ks + 8 * ak + j) * 8 + col] : 0.0f;
                    v[j] = (short)f2bf(f);
                }
                *(short8*)(ws + WS_GFR + t * 64 + ks * 16) = v;
            }
        }
    } else {
        // w2t image: w2t[(e,c)][i] bf16, chunk' = (rc*2+half) ^ ((c>>2)&3)
        const int e2 = t >> 5, colq = (t & 31) * 4;
        const int cc = b - 4;
        const int c = colq + cc;
        const float* w2b = w2 + e2 * 2048 + c;   // w2[e][i][c]
        unsigned pkc[8];
        #pragma unroll
        for (int q = 0; q < 8; ++q) pkc[q] = 0u;
        #pragma unroll
        for (int i = 0; i < 16; ++i)
            pkc[i >> 1] |= (unsigned)f2bf(w2b[i * 128]) << ((i & 1) * 16);
        const int rc = e2 * 128 + c;
        const int a = (c >> 2) & 3;
        *(uint4*)(ws + WS_W2T + (((rc * 2 + 0) ^ a) << 4)) =
            make_uint4(pkc[0], pkc[1], pkc[2], pkc[3]);
        *(uint4*)(ws + WS_W2T + (((rc * 2 + 1) ^ a) << 4)) =
            make_uint4(pkc[4], pkc[5], pkc[6], pkc[7]);
    }
}

//=============================== main kernel ====================================
__global__ __launch_bounds__(256, 2) void moe_fused(
    const float* __restrict__ x, const float* __restrict__ ln_g,
    const float* __restrict__ ln_b, const float* __restrict__ gate_b,
    const char* __restrict__ wsw, float* __restrict__ out)
{
    // 66 KB: 2 blocks/CU
    __shared__ __align__(16) char smem[67584];
    char* pXY = smem;                      // 16KB: xn (bf16), then y (bf16)
    char* pW  = smem + 16384;              // 32KB: w1t, then w2t, then agg f32
    char* pTR = smem + 49152;              // 16KB: bf16 transpose buffer (out2 tiles)
    float* pRW = (float*)(smem + 65536);   // 2KB: routing weights [64][8] f32

    const int t = threadIdx.x;
    const int l = t & 63;
    const int w = t >> 6;
    const int tok0 = blockIdx.x * 64;

    const int colq = (t & 31) * 4;   // P0-layout columns
    const int rsub = t >> 5;         // P0-layout row sub-index

    const int rb = w * 16;           // wave's 16 token rows
    const int col = l & 15;          // MFMA n / lane col (token index in tiles)
    const int ak = l >> 4;           // MFMA k-subgroup / token 4-row group
    const int arow = rb + col;

    //---------------- P0: global loads + staging ----------------
    float4 xv[8];                    // x tile, held in regs to the end
    {
        const float* xb = x + (size_t)tok0 * 128;
        #pragma unroll
        for (int s = 0; s < 8; ++s)
            xv[s] = *(const float4*)(xb + s * 1024 + t * 4);
    }
    float4 g4 = *(const float4*)(ln_g + colq);
    float4 b4 = *(const float4*)(ln_b + colq);

    // w1t image -> pW: linear 32KB block copy (layout already final)
    #pragma unroll
    for (int k = 0; k < 8; ++k)
        *(uint4*)(pW + t * 16 + k * 4096) = *(const uint4*)(wsw + t * 16 + k * 4096);

    // gate fragments from image (4KB, L1-broadcast across waves)
    short8 gfr[4];
    #pragma unroll
    for (int ks = 0; ks < 4; ++ks)
        gfr[ks] = *(const short8*)(wsw + WS_GFR + l * 64 + ks * 16);
    float4 gb4 = *(const float4*)(gate_b + (ak & 1) * 4);

    //---------------- LN in registers, xn -> LDS ----------------
    #pragma unroll
    for (int s = 0; s < 8; ++s) {
        float4 v = xv[s];
        float sm = v.x + v.y + v.z + v.w;
        float sq = v.x*v.x + v.y*v.y + v.z*v.z + v.w*v.w;
        #pragma unroll
        for (int m = 1; m < 32; m <<= 1) {
            sm += __shfl_xor(sm, m, 64);
            sq += __shfl_xor(sq, m, 64);
        }
        float mu = sm * (1.0f / 128.0f);
        float var = sq * (1.0f / 128.0f) - mu * mu;
        float rs = rsqrtf(var + 1e-5f);
        float n0 = (v.x - mu) * rs * g4.x + b4.x;
        float n1 = (v.y - mu) * rs * g4.y + b4.y;
        float n2 = (v.z - mu) * rs * g4.z + b4.z;
        float n3 = (v.w - mu) * rs * g4.w + b4.w;
        unsigned lo = (unsigned)f2bf(n0) | ((unsigned)f2bf(n1) << 16);
        unsigned hi = (unsigned)f2bf(n2) | ((unsigned)f2bf(n3) << 16);
        unsigned long long dvv = (unsigned long long)lo | ((unsigned long long)hi << 32);
        int row = s * 8 + rsub;
        *(unsigned long long*)(pXY + swz(row, colq >> 3) + (colq & 7) * 2) = dvv;
    }

    bar_lds();   // bar1: xn + w1t ready

    const f32x4 zero4 = {0.f, 0.f, 0.f, 0.f};
    const short8 zfrag = {0, 0, 0, 0, 0, 0, 0, 0};

    // xn fragments (lane col = token within wave tile, k = c)
    short8 afr[4];
    #pragma unroll
    for (int ks = 0; ks < 4; ++ks)
        afr[ks] = *(const short8*)(pXY + swz(arow, ks * 4 + ak));

    //---------------- gating (swapped): D[e][token] ----------------
    f32x4 accg = zero4;
    #pragma unroll
    for (int ks = 0; ks < 4; ++ks)
        accg = __builtin_amdgcn_mfma_f32_16x16x32_bf16(gfr[ks], afr[ks], accg, 0, 0, 0);

    const size_t trow = (size_t)(tok0 + arow);
    {
        // lane holds logits for token trow, experts e = ak*4 + r (valid ak<2)
        float lg0 = accg[0] + gb4.x;
        float lg1 = accg[1] + gb4.y;
        float lg2 = accg[2] + gb4.z;
        float lg3 = accg[3] + gb4.w;
        if (ak < 2) {
            f32x4 lgv = {lg0, lg1, lg2, lg3};
            *(f32x4*)(out + O1_OFF + trow * 8 + ak * 4) = lgv;
        }
        float mx = fmaxf(fmaxf(lg0, lg1), fmaxf(lg2, lg3));
        mx = fmaxf(mx, __shfl_xor(mx, 16, 64));
        float ex0 = __expf(lg0 - mx), ex1 = __expf(lg1 - mx);
        float ex2 = __expf(lg2 - mx), ex3 = __expf(lg3 - mx);
        float sm = ex0 + ex1 + ex2 + ex3;
        sm += __shfl_xor(sm, 16, 64);
        float inv = 1.0f / sm;
        if (ak < 2) {
            f32x4 pv = {ex0 * inv, ex1 * inv, ex2 * inv, ex3 * inv};
            *(f32x4*)(pRW + arow * 8 + ak * 4) = pv;
        }
    }

    //---------------- stage B (swapped): y^T per token in-lane ----------------
    f32x4 accb[8];
    #pragma unroll
    for (int nt = 0; nt < 8; ++nt) accb[nt] = zero4;
    #pragma unroll
    for (int ks = 0; ks < 4; ++ks)
        #pragma unroll
        for (int nt = 0; nt < 8; ++nt) {
            short8 wfr = *(const short8*)(pW + swz(nt * 16 + col, ks * 4 + ak));
            accb[nt] = __builtin_amdgcn_mfma_f32_16x16x32_bf16(wfr, afr[ks], accb[nt], 0, 0, 0);
        }

    // exact-erf GELU; lane holds token arow, ei = nt*16 + ak*4 + r -> 8B packed write
    #pragma unroll
    for (int nt = 0; nt < 8; ++nt) {
        float y0 = accb[nt][0], y1 = accb[nt][1], y2 = accb[nt][2], y3 = accb[nt][3];
        y0 = 0.5f * y0 * (1.0f + erff(y0 * 0.70710678118654752f));
        y1 = 0.5f * y1 * (1.0f + erff(y1 * 0.70710678118654752f));
        y2 = 0.5f * y2 * (1.0f + erff(y2 * 0.70710678118654752f));
        y3 = 0.5f * y3 * (1.0f + erff(y3 * 0.70710678118654752f));
        unsigned lo = (unsigned)f2bf(y0) | ((unsigned)f2bf(y1) << 16);
        unsigned hi = (unsigned)f2bf(y2) | ((unsigned)f2bf(y3) << 16);
        unsigned long long dv = (unsigned long long)lo | ((unsigned long long)hi << 32);
        *(unsigned long long*)(pXY + swz(arow, nt * 2 + (ak >> 1)) + (ak & 1) * 8) = dv;
    }

    bar_lds();   // bar2: all stage-B w1t reads done -> w1t region reusable

    // w2t image -> pW: linear 32KB block copy (layout already final)
    #pragma unroll
    for (int k = 0; k < 8; ++k)
        *(uint4*)(pW + t * 16 + k * 4096) = *(const uint4*)(wsw + WS_W2T + t * 16 + k * 4096);

    bar_lds();   // bar3: w2t + y + pRW ready

    //---------------- P4: per-expert GEMM -> LDS transpose -> full-line stores ---
    f32x4 agg[8];
    #pragma unroll
    for (int nt = 0; nt < 8; ++nt) agg[nt] = zero4;

    #pragma unroll
    for (int e = 0; e < 8; ++e) {
        float rwe[4];
        #pragma unroll
        for (int r = 0; r < 4; ++r)
            rwe[r] = pRW[(rb + ak * 4 + r) * 8 + e];
        short8 alo = *(const short8*)(pXY + swz(arow, 2 * e + (ak & 1)));
        short8 af = (ak < 2) ? alo : zfrag;    // K=16 padded to 32
        f32x4 ot[8];
        #pragma unroll
        for (int nt = 0; nt < 8; ++nt) {
            int c = nt * 16 + col;
            int rc = e * 128 + c;
            int a = (c >> 2) & 3;
            short8 blo = *(const short8*)(pW + (((rc * 2 + (ak & 1)) ^ a) << 4));
            short8 bf = (ak < 2) ? blo : zfrag;
            ot[nt] = __builtin_amdgcn_mfma_f32_16x16x32_bf16(af, bf, zero4, 0, 0, 0);
            #pragma unroll
            for (int r = 0; r < 4; ++r)
                agg[nt][r] += rwe[r] * ot[nt][r];
        }
        // MFMA-layout -> bf16 transpose slice (wave-private rows)
        #pragma unroll
        for (int nt = 0; nt < 8; ++nt)
            #pragma unroll
            for (int r = 0; r < 4; ++r)
                *(unsigned short*)(pTR + tswz(rb + ak * 4 + r, nt * 16 + col)) = f2bf(ot[nt][r]);
        fence_lds();   // drain DS writes + block compiler reordering (TBAA)
        // read back row-major: 2 full token-expert rows per instruction
        #pragma unroll
        for (int i2 = 0; i2 < 8; ++i2) {
            int row = rb + i2 * 2 + (l >> 5);
            int c0 = (l & 31) * 4;
            unsigned long long raw = *(const unsigned long long*)(pTR + tswz(row, c0));
            unsigned lo = (unsigned)raw, hi = (unsigned)(raw >> 32);
            f32x4 v;
            v[0] = __builtin_bit_cast(float, lo << 16);
            v[1] = __builtin_bit_cast(float, lo & 0xffff0000u);
            v[2] = __builtin_bit_cast(float, hi << 16);
            v[3] = __builtin_bit_cast(float, hi & 0xffff0000u);
            __builtin_nontemporal_store(v,
                (f32x4*)(out + O2_OFF + (size_t)(tok0 + row) * 1024 + e * 128 + c0));
        }
        asm volatile("" ::: "memory");   // keep next expert's writes after these reads
    }

    bar_lds();   // bar4: all waves' w2t reads done -> pW reusable for agg (f32)

    //---------------- epilogue: f32 agg through pW (R0-verified scheme) ----------
    #pragma unroll
    for (int nt = 0; nt < 8; ++nt) {
        int c = nt * 16 + col;
        #pragma unroll
        for (int r = 0; r < 4; ++r) {
            int row = rb + ak * 4 + r;
            *(float*)(pW + row * 512 + ((c << 2) ^ ((row & 4) << 2))) = agg[nt][r];
        }
    }

    bar_lds();   // bar5: agg tile ready in P0 layout

    #pragma unroll
    for (int s = 0; s < 8; ++s) {
        int row = s * 8 + rsub;
        f32x4 a4 = *(const f32x4*)(pW + row * 512 + ((colq << 2) ^ ((row & 4) << 2)));
        f32x4 o;
        o[0] = xv[s].x + a4[0];
        o[1] = xv[s].y + a4[1];
        o[2] = xv[s].z + a4[2];
        o[3] = xv[s].w + a4[3];
        __builtin_nontemporal_store(o,
            (f32x4*)(out + (size_t)(tok0 + row) * 128 + colq));
    }
}

extern "C" void kernel_launch(void* const* d_in, const int* in_sizes, int n_in,
                              void* d_out, int out_size, void* d_ws, size_t ws_size,
                              hipStream_t stream) {
    const float* x      = (const float*)d_in[0];
    const float* ln_g   = (const float*)d_in[1];
    const float* ln_b   = (const float*)d_in[2];
    const float* gate_w = (const float*)d_in[3];
    const float* gate_b = (const float*)d_in[4];
    const float* w1     = (const float*)d_in[5];
    const float* w2     = (const float*)d_in[6];
    float* out = (float*)d_out;
    char* ws = (char*)d_ws;
    (void)in_sizes; (void)n_in; (void)out_size; (void)ws_size;
    moe_prep<<<dim3(8), dim3(256), 0, stream>>>(gate_w, w1, w2, ws);
    moe_fused<<<dim3(1024), dim3(256), 0, stream>>>(x, ln_g, ln_b, gate_b, ws, out);
}